// Round 2
// baseline (234.106 us; speedup 1.0000x reference)
//
#include <hip/hip_runtime.h>

#define FDIM 16

// ---------------------------------------------------------------------------
// Kernel 0: zero-fill d_out (hi accumulator). Own kernel instead of
// hipMemsetAsync to stay inside the graph-capture-safe API surface.
// ---------------------------------------------------------------------------
__global__ void zero_kernel(float4* __restrict__ p, long long n4) {
  long long i = (long long)blockIdx.x * blockDim.x + threadIdx.x;
  if (i < n4) p[i] = make_float4(0.f, 0.f, 0.f, 0.f);
}

// ---------------------------------------------------------------------------
// Kernel 1: sorted-COO SpMM  hi[r,:] += val[e] * x[col[e],:]
// 16 lanes per group = one lane per feature. Each group walks a contiguous
// segment of SEG edges, accumulating runs of equal row in a register and
// flushing via atomicAdd on row change (rows sorted -> ~seg/avg_deg flushes).
// NOTE: adj_row/adj_col arrive as int32 (JAX x64 disabled downcasts int64).
// ---------------------------------------------------------------------------
__global__ void spmm_kernel(const int* __restrict__ rows,
                            const int* __restrict__ cols,
                            const float* __restrict__ vals,
                            const float* __restrict__ x,
                            float* __restrict__ hi,
                            long long nedge, int seg) {
  long long gid = (long long)blockIdx.x * (blockDim.x >> 4) + (threadIdx.x >> 4);
  int f = threadIdx.x & 15;
  long long e0 = gid * (long long)seg;
  if (e0 >= nedge) return;
  long long e1 = e0 + seg;
  if (e1 > nedge) e1 = nedge;

  int cur = rows[e0];
  float acc = 0.f;
  for (long long e = e0; e < e1; ++e) {
    int r = rows[e];
    int c = cols[e];
    float v = vals[e];
    float xv = x[(long long)c * FDIM + f];
    if (r != cur) {
      atomicAdd(&hi[(long long)cur * FDIM + f], acc);
      acc = 0.f;
      cur = r;
    }
    acc = fmaf(v, xv, acc);
  }
  atomicAdd(&hi[(long long)cur * FDIM + f], acc);
}

// ---------------------------------------------------------------------------
// Kernel 2: per-node epilogue, in place on hio (= hi on input, out on output).
//   alpha = hi . fc_w + fc_b
//   theta = log(lamda/l + 1)
//   s     = concat(hi,h0) @ W           (32x16, W via uniform scalar loads)
//   out   = theta*s + (1-theta)*((1-alpha)*hi + alpha*h0) + x
// Each thread owns one node: reads its 16 floats, then overwrites them.
// ---------------------------------------------------------------------------
__global__ void fuse_kernel(float* __restrict__ hio,
                            const float* __restrict__ h0,
                            const float* __restrict__ x,
                            const float* __restrict__ weight,
                            const float* __restrict__ fc_w,
                            const float* __restrict__ fc_b,
                            const float* __restrict__ lamda,
                            const int* __restrict__ lpar,
                            int n) {
  int i = blockIdx.x * blockDim.x + threadIdx.x;
  if (i >= n) return;

  float theta = logf(lamda[0] / (float)lpar[0] + 1.0f);
  float fcb = fc_b[0];

  float hiv[FDIM], h0v[FDIM], xv[FDIM];
  {
    const float4* p = reinterpret_cast<const float4*>(hio + (size_t)i * FDIM);
    const float4* q = reinterpret_cast<const float4*>(h0 + (size_t)i * FDIM);
    const float4* r = reinterpret_cast<const float4*>(x + (size_t)i * FDIM);
#pragma unroll
    for (int j = 0; j < 4; ++j) {
      float4 a = p[j];
      hiv[4 * j + 0] = a.x; hiv[4 * j + 1] = a.y; hiv[4 * j + 2] = a.z; hiv[4 * j + 3] = a.w;
      float4 b = q[j];
      h0v[4 * j + 0] = b.x; h0v[4 * j + 1] = b.y; h0v[4 * j + 2] = b.z; h0v[4 * j + 3] = b.w;
      float4 c = r[j];
      xv[4 * j + 0] = c.x; xv[4 * j + 1] = c.y; xv[4 * j + 2] = c.z; xv[4 * j + 3] = c.w;
    }
  }

  // alpha gate (fc_w[k] is wave-uniform -> scalar loads)
  float alpha = fcb;
#pragma unroll
  for (int k = 0; k < FDIM; ++k) alpha = fmaf(hiv[k], fc_w[k], alpha);

  // s = concat(hi, h0) @ W   -- weight[] accesses are wave-uniform -> SGPRs
  float s[FDIM];
#pragma unroll
  for (int f = 0; f < FDIM; ++f) s[f] = 0.f;
#pragma unroll
  for (int k = 0; k < FDIM; ++k) {
#pragma unroll
    for (int f = 0; f < FDIM; ++f) s[f] = fmaf(hiv[k], weight[k * FDIM + f], s[f]);
  }
#pragma unroll
  for (int k = 0; k < FDIM; ++k) {
#pragma unroll
    for (int f = 0; f < FDIM; ++f) s[f] = fmaf(h0v[k], weight[(FDIM + k) * FDIM + f], s[f]);
  }

  float omt = 1.f - theta;
  float oma = 1.f - alpha;
  float ov[FDIM];
#pragma unroll
  for (int f = 0; f < FDIM; ++f) {
    float r = oma * hiv[f] + alpha * h0v[f];
    ov[f] = fmaf(theta, s[f], omt * r) + xv[f];
  }

  float4* o = reinterpret_cast<float4*>(hio + (size_t)i * FDIM);
#pragma unroll
  for (int j = 0; j < 4; ++j) {
    float4 c;
    c.x = ov[4 * j + 0]; c.y = ov[4 * j + 1]; c.z = ov[4 * j + 2]; c.w = ov[4 * j + 3];
    o[j] = c;
  }
}

extern "C" void kernel_launch(void* const* d_in, const int* in_sizes, int n_in,
                              void* d_out, int out_size, void* d_ws, size_t ws_size,
                              hipStream_t stream) {
  const float* x        = (const float*)d_in[0];
  const float* h0       = (const float*)d_in[1];
  const int* adj_row    = (const int*)d_in[2];   // int32 (JAX x64 disabled)
  const int* adj_col    = (const int*)d_in[3];   // int32
  const float* adj_val  = (const float*)d_in[4];
  const float* weight   = (const float*)d_in[5];
  const float* fc_w     = (const float*)d_in[6];
  const float* fc_b     = (const float*)d_in[7];
  const float* lamda    = (const float*)d_in[8];
  const int* lpar       = (const int*)d_in[9];

  int n = in_sizes[0] / FDIM;
  long long nedge = in_sizes[2];
  float* out = (float*)d_out;

  // Zero hi accumulator (d_out) every call — harness poisons once, never
  // re-poisons between timed replays.
  long long n4 = (long long)out_size / 4;
  int zb = (int)((n4 + 255) / 256);
  zero_kernel<<<zb, 256, 0, stream>>>((float4*)out, n4);

  const int SEG = 256;                     // edges per 16-lane group
  long long ngroups = (nedge + SEG - 1) / SEG;
  int groups_per_block = 256 / 16;
  long long nblocks = (ngroups + groups_per_block - 1) / groups_per_block;
  spmm_kernel<<<(int)nblocks, 256, 0, stream>>>(adj_row, adj_col, adj_val, x,
                                                out, nedge, SEG);

  int fb = (n + 255) / 256;
  fuse_kernel<<<fb, 256, 0, stream>>>(out, h0, x, weight, fc_w, fc_b,
                                      lamda, lpar, n);
}

// Round 3
// 206.156 us; speedup vs baseline: 1.1356x; 1.1356x over previous
//
#include <hip/hip_runtime.h>

#define FDIM 16
#define SEG 128   // edges per 16-lane group

// ---------------------------------------------------------------------------
// Kernel 0: zero-fill d_out (hi accumulator). Own kernel (graph-capture-safe).
// ---------------------------------------------------------------------------
__global__ void zero_kernel(float4* __restrict__ p, long long n4) {
  long long i = (long long)blockIdx.x * blockDim.x + threadIdx.x;
  if (i < n4) p[i] = make_float4(0.f, 0.f, 0.f, 0.f);
}

// ---------------------------------------------------------------------------
// Kernel 1: sorted-COO SpMM  hi[r,:] += val[e] * x[col[e],:]
// 16 lanes/group = one lane per feature; group walks SEG contiguous edges.
// Unroll-8 with vectorized edge loads: 6 vector loads + 8 independent
// gathers in flight per iteration (vs 1 before). Sorted rows -> if the last
// row of the chunk equals the current run row, the whole chunk is one run
// (fast path, no flush checks). Flush run to hi via atomicAdd on row change.
// ---------------------------------------------------------------------------
__global__ __launch_bounds__(256) void spmm_kernel(
    const int* __restrict__ rows,
    const int* __restrict__ cols,
    const float* __restrict__ vals,
    const float* __restrict__ x,
    float* __restrict__ hi,
    long long nedge) {
  long long gid = (long long)blockIdx.x * 16 + (threadIdx.x >> 4);
  int f = threadIdx.x & 15;
  long long e0 = gid * SEG;
  if (e0 >= nedge) return;
  long long e1 = e0 + SEG;
  if (e1 > nedge) e1 = nedge;

  int cur = rows[e0];
  float acc = 0.f;
  long long e = e0;

#define FLUSH_STEP(r_, v_, x_)                                      \
  if (r_ != cur) {                                                  \
    atomicAdd(&hi[cur * FDIM + f], acc);                            \
    acc = 0.f;                                                      \
    cur = r_;                                                       \
  }                                                                 \
  acc = fmaf(v_, x_, acc);

  for (; e + 8 <= e1; e += 8) {
    int4 ra = *reinterpret_cast<const int4*>(rows + e);
    int4 rb = *reinterpret_cast<const int4*>(rows + e + 4);
    int4 ca = *reinterpret_cast<const int4*>(cols + e);
    int4 cb = *reinterpret_cast<const int4*>(cols + e + 4);
    float4 va = *reinterpret_cast<const float4*>(vals + e);
    float4 vb = *reinterpret_cast<const float4*>(vals + e + 4);
    // 8 independent gathers issued up front (x is L3-resident, 32 MB)
    float xa0 = x[ca.x * FDIM + f];
    float xa1 = x[ca.y * FDIM + f];
    float xa2 = x[ca.z * FDIM + f];
    float xa3 = x[ca.w * FDIM + f];
    float xb0 = x[cb.x * FDIM + f];
    float xb1 = x[cb.y * FDIM + f];
    float xb2 = x[cb.z * FDIM + f];
    float xb3 = x[cb.w * FDIM + f];

    if (rb.w == cur) {
      // whole chunk continues the current run (rows sorted -> monotone)
      acc = fmaf(va.x, xa0, acc);
      acc = fmaf(va.y, xa1, acc);
      acc = fmaf(va.z, xa2, acc);
      acc = fmaf(va.w, xa3, acc);
      acc = fmaf(vb.x, xb0, acc);
      acc = fmaf(vb.y, xb1, acc);
      acc = fmaf(vb.z, xb2, acc);
      acc = fmaf(vb.w, xb3, acc);
    } else {
      FLUSH_STEP(ra.x, va.x, xa0)
      FLUSH_STEP(ra.y, va.y, xa1)
      FLUSH_STEP(ra.z, va.z, xa2)
      FLUSH_STEP(ra.w, va.w, xa3)
      FLUSH_STEP(rb.x, vb.x, xb0)
      FLUSH_STEP(rb.y, vb.y, xb1)
      FLUSH_STEP(rb.z, vb.z, xb2)
      FLUSH_STEP(rb.w, vb.w, xb3)
    }
  }
  for (; e < e1; ++e) {  // tail (never taken: 8M % 8 == 0, kept for safety)
    int r = rows[e];
    int c = cols[e];
    float v = vals[e];
    float xv = x[c * FDIM + f];
    FLUSH_STEP(r, v, xv)
  }
  atomicAdd(&hi[cur * FDIM + f], acc);
#undef FLUSH_STEP
}

// ---------------------------------------------------------------------------
// Kernel 2: per-node epilogue, in place on hio (= hi on input, out on output).
// ---------------------------------------------------------------------------
__global__ void fuse_kernel(float* __restrict__ hio,
                            const float* __restrict__ h0,
                            const float* __restrict__ x,
                            const float* __restrict__ weight,
                            const float* __restrict__ fc_w,
                            const float* __restrict__ fc_b,
                            const float* __restrict__ lamda,
                            const int* __restrict__ lpar,
                            int n) {
  int i = blockIdx.x * blockDim.x + threadIdx.x;
  if (i >= n) return;

  float theta = logf(lamda[0] / (float)lpar[0] + 1.0f);
  float fcb = fc_b[0];

  float hiv[FDIM], h0v[FDIM], xv[FDIM];
  {
    const float4* p = reinterpret_cast<const float4*>(hio + (size_t)i * FDIM);
    const float4* q = reinterpret_cast<const float4*>(h0 + (size_t)i * FDIM);
    const float4* r = reinterpret_cast<const float4*>(x + (size_t)i * FDIM);
#pragma unroll
    for (int j = 0; j < 4; ++j) {
      float4 a = p[j];
      hiv[4 * j + 0] = a.x; hiv[4 * j + 1] = a.y; hiv[4 * j + 2] = a.z; hiv[4 * j + 3] = a.w;
      float4 b = q[j];
      h0v[4 * j + 0] = b.x; h0v[4 * j + 1] = b.y; h0v[4 * j + 2] = b.z; h0v[4 * j + 3] = b.w;
      float4 c = r[j];
      xv[4 * j + 0] = c.x; xv[4 * j + 1] = c.y; xv[4 * j + 2] = c.z; xv[4 * j + 3] = c.w;
    }
  }

  float alpha = fcb;
#pragma unroll
  for (int k = 0; k < FDIM; ++k) alpha = fmaf(hiv[k], fc_w[k], alpha);

  float s[FDIM];
#pragma unroll
  for (int f = 0; f < FDIM; ++f) s[f] = 0.f;
#pragma unroll
  for (int k = 0; k < FDIM; ++k) {
#pragma unroll
    for (int f = 0; f < FDIM; ++f) s[f] = fmaf(hiv[k], weight[k * FDIM + f], s[f]);
  }
#pragma unroll
  for (int k = 0; k < FDIM; ++k) {
#pragma unroll
    for (int f = 0; f < FDIM; ++f) s[f] = fmaf(h0v[k], weight[(FDIM + k) * FDIM + f], s[f]);
  }

  float omt = 1.f - theta;
  float oma = 1.f - alpha;
  float ov[FDIM];
#pragma unroll
  for (int f = 0; f < FDIM; ++f) {
    float r = oma * hiv[f] + alpha * h0v[f];
    ov[f] = fmaf(theta, s[f], omt * r) + xv[f];
  }

  float4* o = reinterpret_cast<float4*>(hio + (size_t)i * FDIM);
#pragma unroll
  for (int j = 0; j < 4; ++j) {
    float4 c;
    c.x = ov[4 * j + 0]; c.y = ov[4 * j + 1]; c.z = ov[4 * j + 2]; c.w = ov[4 * j + 3];
    o[j] = c;
  }
}

extern "C" void kernel_launch(void* const* d_in, const int* in_sizes, int n_in,
                              void* d_out, int out_size, void* d_ws, size_t ws_size,
                              hipStream_t stream) {
  const float* x        = (const float*)d_in[0];
  const float* h0       = (const float*)d_in[1];
  const int* adj_row    = (const int*)d_in[2];   // int32 (JAX x64 disabled)
  const int* adj_col    = (const int*)d_in[3];   // int32
  const float* adj_val  = (const float*)d_in[4];
  const float* weight   = (const float*)d_in[5];
  const float* fc_w     = (const float*)d_in[6];
  const float* fc_b     = (const float*)d_in[7];
  const float* lamda    = (const float*)d_in[8];
  const int* lpar       = (const int*)d_in[9];

  int n = in_sizes[0] / FDIM;
  long long nedge = in_sizes[2];
  float* out = (float*)d_out;

  // Zero hi accumulator (d_out) every call — harness poisons once, never
  // re-poisons between timed replays.
  long long n4 = (long long)out_size / 4;
  int zb = (int)((n4 + 255) / 256);
  zero_kernel<<<zb, 256, 0, stream>>>((float4*)out, n4);

  long long ngroups = (nedge + SEG - 1) / SEG;
  long long nblocks = (ngroups + 15) / 16;   // 16 groups (256 threads) / block
  spmm_kernel<<<(int)nblocks, 256, 0, stream>>>(adj_row, adj_col, adj_val, x,
                                                out, nedge);

  int fb = (n + 255) / 256;
  fuse_kernel<<<fb, 256, 0, stream>>>(out, h0, x, weight, fc_w, fc_b,
                                      lamda, lpar, n);
}